// Round 1
// baseline (1334.635 us; speedup 1.0000x reference)
//
#include <hip/hip_runtime.h>
#include <cstdint>
#include <cstddef>

// Problem dims (fixed)
#define T_TOKENS 8192
#define H_DIM    1024
#define F_DIM    4096
#define E_NUM    8

typedef __bf16 bf16x8 __attribute__((ext_vector_type(8)));
typedef float  f32x4  __attribute__((ext_vector_type(4)));

#define AS_GLOBAL(p) ((const __attribute__((address_space(1))) void*)(p))
#define AS_LDS(p)    ((__attribute__((address_space(3))) void*)(p))

__device__ inline unsigned short f2b(float f) {
  unsigned int u = __float_as_uint(f);
  unsigned int r = (u + 0x7fffu + ((u >> 16) & 1u)) >> 16;   // RNE
  return (unsigned short)r;
}
__device__ inline float b2f(unsigned short u) {
  return __uint_as_float(((unsigned int)u) << 16);
}
__device__ inline float gelu_tanh(float v) {
  float c = v + 0.044715f * v * v * v;
  return 0.5f * v * (1.0f + tanhf(0.7978845608028654f * c));
}

// ---------------------------------------------------------------------------
// Transpose + fp32->bf16 cast:  in [E][R][C] fp32  ->  out [E][C][R] bf16
// ---------------------------------------------------------------------------
__global__ __launch_bounds__(256) void transpose_cast_kernel(
    const float* __restrict__ in, unsigned short* __restrict__ out, int R, int C)
{
  __shared__ float tile[64][65];
  const int e  = blockIdx.z;
  const int c0 = blockIdx.x * 64;
  const int r0 = blockIdx.y * 64;
  const float* src = in + (size_t)e * R * C;
  unsigned short* dst = out + (size_t)e * R * C;
  const int tid = threadIdx.x;
  const int rl  = tid >> 4;
  const int cl4 = (tid & 15) * 4;
#pragma unroll
  for (int i = 0; i < 4; ++i) {
    float4 v = *(const float4*)(src + (size_t)(r0 + rl + i * 16) * C + c0 + cl4);
    tile[rl + i * 16][cl4 + 0] = v.x;
    tile[rl + i * 16][cl4 + 1] = v.y;
    tile[rl + i * 16][cl4 + 2] = v.z;
    tile[rl + i * 16][cl4 + 3] = v.w;
  }
  __syncthreads();
  const int cl = tid >> 2;
  const int rb = (tid & 3) * 16;
#pragma unroll
  for (int j = 0; j < 4; ++j) {
    ushort4 u;
    u.x = f2b(tile[rb + j * 4 + 0][cl]);
    u.y = f2b(tile[rb + j * 4 + 1][cl]);
    u.z = f2b(tile[rb + j * 4 + 2][cl]);
    u.w = f2b(tile[rb + j * 4 + 3][cl]);
    *(ushort4*)(dst + (size_t)(c0 + cl) * R + r0 + rb + j * 4) = u;
  }
}

// ---------------------------------------------------------------------------
// Router: logits (fp32) -> softmax -> top-2; also casts x to bf16.
// One wave per token-group; 8 tokens per wave; grid 256 x 256 threads.
// ---------------------------------------------------------------------------
__global__ __launch_bounds__(256) void router_kernel(
    const float* __restrict__ x, const float* __restrict__ rw,
    unsigned short* __restrict__ xb, int* __restrict__ top_e, float* __restrict__ top_p)
{
  __shared__ float lrw[H_DIM * 9];   // padded stride 9 to spread banks
  const int tid = threadIdx.x;
  for (int r = tid; r < H_DIM; r += 256) {
    const float* s = rw + r * 8;
    float4 a = *(const float4*)(s);
    float4 b = *(const float4*)(s + 4);
    float* d = &lrw[r * 9];
    d[0] = a.x; d[1] = a.y; d[2] = a.z; d[3] = a.w;
    d[4] = b.x; d[5] = b.y; d[6] = b.z; d[7] = b.w;
  }
  __syncthreads();
  const int lane = tid & 63, wid = tid >> 6;
  for (int i = 0; i < 8; ++i) {
    const int t = blockIdx.x * 32 + wid * 8 + i;
    float acc[8] = {0.f, 0.f, 0.f, 0.f, 0.f, 0.f, 0.f, 0.f};
    const float* xrow = x + (size_t)t * H_DIM;
    unsigned short* xbrow = xb + (size_t)t * H_DIM;
#pragma unroll
    for (int j = 0; j < 16; ++j) {
      int h = j * 64 + lane;
      float xv = xrow[h];
      xbrow[h] = f2b(xv);
      const float* rr = &lrw[h * 9];
#pragma unroll
      for (int e = 0; e < 8; ++e) acc[e] += xv * rr[e];
    }
#pragma unroll
    for (int e = 0; e < 8; ++e) {
#pragma unroll
      for (int s = 32; s > 0; s >>= 1) acc[e] += __shfl_xor(acc[e], s, 64);
    }
    if (lane == 0) {
      float mx = acc[0];
      for (int e = 1; e < 8; ++e) mx = fmaxf(mx, acc[e]);
      float p[8]; float sum = 0.f;
      for (int e = 0; e < 8; ++e) { p[e] = expf(acc[e] - mx); sum += p[e]; }
      float inv = 1.0f / sum;
      int i1 = 0; float b1 = p[0];
      for (int e = 1; e < 8; ++e) if (p[e] > b1) { b1 = p[e]; i1 = e; }
      int i2 = (i1 == 0) ? 1 : 0; float b2 = p[i2];
      for (int e = 0; e < 8; ++e) if (e != i1 && p[e] > b2) { b2 = p[e]; i2 = e; }
      top_e[2 * t]     = i1; top_p[2 * t]     = b1 * inv;
      top_e[2 * t + 1] = i2; top_p[2 * t + 1] = b2 * inv;
    }
  }
}

// ---------------------------------------------------------------------------
// Count tokens per expert + exclusive prefix -> offsets; zero cursors.
// ---------------------------------------------------------------------------
__global__ __launch_bounds__(256) void count_offsets_kernel(
    const int* __restrict__ top_e, int* __restrict__ counts,
    int* __restrict__ offsets, int* __restrict__ cursor)
{
  __shared__ int c[E_NUM];
  if (threadIdx.x < E_NUM) c[threadIdx.x] = 0;
  __syncthreads();
  for (int i = threadIdx.x; i < 2 * T_TOKENS; i += 256) atomicAdd(&c[top_e[i]], 1);
  __syncthreads();
  if (threadIdx.x == 0) {
    int o = 0;
    for (int e = 0; e < E_NUM; ++e) {
      counts[e] = c[e]; offsets[e] = o; o += c[e]; cursor[e] = 0;
    }
  }
}

// ---------------------------------------------------------------------------
// Dispatch: assign each (token, k) a slot in its expert's contiguous segment.
// Block-aggregated atomics (8 global atomics per block).
// ---------------------------------------------------------------------------
__global__ __launch_bounds__(256) void assign_kernel(
    const int* __restrict__ top_e, const float* __restrict__ top_p,
    const int* __restrict__ offsets, int* __restrict__ cursor,
    int* __restrict__ map, float* __restrict__ gate, int* __restrict__ slot_of)
{
  __shared__ int lc[E_NUM], lb[E_NUM];
  const int tid = threadIdx.x;
  const int t = blockIdx.x * 256 + tid;
  if (tid < E_NUM) lc[tid] = 0;
  __syncthreads();
  int e0 = top_e[2 * t], e1 = top_e[2 * t + 1];
  int p0 = atomicAdd(&lc[e0], 1);
  int p1 = atomicAdd(&lc[e1], 1);
  __syncthreads();
  if (tid < E_NUM) lb[tid] = atomicAdd(&cursor[tid], lc[tid]);
  __syncthreads();
  int s0 = offsets[e0] + lb[e0] + p0;
  int s1 = offsets[e1] + lb[e1] + p1;
  map[s0] = t; gate[s0] = top_p[2 * t];
  map[s1] = t; gate[s1] = top_p[2 * t + 1];
  slot_of[2 * t] = s0; slot_of[2 * t + 1] = s1;
}

// ---------------------------------------------------------------------------
// Grouped GEMM, m97 structure: 128x128 tile, BK=64, 4 waves of 64x64,
// mfma_f32_16x16x32_bf16, global_load_lds width-16 staging.
//   A [rows][KD] bf16 (rows indexed via map for fc1, direct slots for fc2)
//   Bt [E][ND][KD] bf16 (B^T layout: fragment reads K-contiguous)
//   C [slot][ND] bf16; epilogue = gelu (fc1) or gate-scale (fc2)
// ---------------------------------------------------------------------------
template <int KD, int ND, bool USE_MAP, bool GELU>
__global__ __launch_bounds__(256) void moe_gemm_kernel(
    const unsigned short* __restrict__ A, const unsigned short* __restrict__ Bt,
    const int* __restrict__ map, const float* __restrict__ gate,
    const int* __restrict__ counts, const int* __restrict__ offsets,
    unsigned short* __restrict__ C)
{
  __shared__ unsigned short lsA[128 * 64];
  __shared__ unsigned short lsB[128 * 64];
  const int e   = blockIdx.z;
  const int cnt = counts[e];
  const int tile_m = blockIdx.x;
  if (tile_m * 128 >= cnt) return;
  const int off    = offsets[e];
  const int tile_n = blockIdx.y;
  const int tid    = threadIdx.x;

  // Staging sources: chunk = it*256 + tid ; row = chunk>>3 ; 8-elem col group = tid&7
  const unsigned short* aSrc[4];
  const unsigned short* bSrc[4];
  const int c8 = (tid & 7) * 8;
#pragma unroll
  for (int it = 0; it < 4; ++it) {
    int r  = it * 32 + (tid >> 3);
    int rm = tile_m * 128 + r;
    if (rm > cnt - 1) rm = cnt - 1;               // clamp padded rows
    int arow = USE_MAP ? map[off + rm] : (off + rm);
    aSrc[it] = A + (size_t)arow * KD + c8;
    int rn = tile_n * 128 + r;
    bSrc[it] = Bt + (size_t)e * ND * KD + (size_t)rn * KD + c8;
  }

  const int lane = tid & 63;
  const int wid  = tid >> 6;
  const int wm = wid >> 1, wn = wid & 1;          // 2x2 wave grid, 64x64 each
  const int lr = lane & 15, kg = lane >> 4;
  const unsigned short* pA = lsA + (wm * 64 + lr) * 64 + kg * 8;
  const unsigned short* pB = lsB + (wn * 64 + lr) * 64 + kg * 8;

  f32x4 acc[4][4];
#pragma unroll
  for (int mi = 0; mi < 4; ++mi)
#pragma unroll
    for (int ni = 0; ni < 4; ++ni) acc[mi][ni] = (f32x4){0.f, 0.f, 0.f, 0.f};

#pragma unroll 1
  for (int k0 = 0; k0 < KD; k0 += 64) {
    __syncthreads();
#pragma unroll
    for (int it = 0; it < 4; ++it)
      __builtin_amdgcn_global_load_lds(AS_GLOBAL(aSrc[it] + k0),
                                       AS_LDS(lsA + (it * 256 + tid) * 8), 16, 0, 0);
#pragma unroll
    for (int it = 0; it < 4; ++it)
      __builtin_amdgcn_global_load_lds(AS_GLOBAL(bSrc[it] + k0),
                                       AS_LDS(lsB + (it * 256 + tid) * 8), 16, 0, 0);
    __syncthreads();   // compiler inserts s_waitcnt vmcnt(0) before s_barrier
#pragma unroll
    for (int ks = 0; ks < 2; ++ks) {
      bf16x8 aF[4], bF[4];
#pragma unroll
      for (int i = 0; i < 4; ++i) aF[i] = *(const bf16x8*)(pA + i * 16 * 64 + ks * 32);
#pragma unroll
      for (int i = 0; i < 4; ++i) bF[i] = *(const bf16x8*)(pB + i * 16 * 64 + ks * 32);
#pragma unroll
      for (int mi = 0; mi < 4; ++mi)
#pragma unroll
        for (int ni = 0; ni < 4; ++ni)
          acc[mi][ni] = __builtin_amdgcn_mfma_f32_16x16x32_bf16(aF[mi], bF[ni],
                                                                acc[mi][ni], 0, 0, 0);
    }
  }

  // Epilogue.  C/D layout: col = lane&15, row = (lane>>4)*4 + reg  [m89/m91]
#pragma unroll
  for (int mi = 0; mi < 4; ++mi) {
#pragma unroll
    for (int r = 0; r < 4; ++r) {
      int mrow = wm * 64 + mi * 16 + kg * 4 + r;
      int gm = tile_m * 128 + mrow;
      if (gm < cnt) {
        size_t crow = (size_t)(off + gm);
        float gv = 1.0f;
        if (!GELU) gv = gate[crow];
#pragma unroll
        for (int ni = 0; ni < 4; ++ni) {
          int col = tile_n * 128 + wn * 64 + ni * 16 + lr;
          float v = acc[mi][ni][r];
          if (GELU) v = gelu_tanh(v); else v *= gv;
          C[crow * ND + col] = f2b(v);
        }
      }
    }
  }
}

// ---------------------------------------------------------------------------
// Combine: out[t] = y[slot0(t)] + y[slot1(t)]   (gates already applied)
// ---------------------------------------------------------------------------
__global__ __launch_bounds__(256) void combine_kernel(
    const unsigned short* __restrict__ y, const int* __restrict__ slot_of,
    float* __restrict__ out)
{
  const int t  = blockIdx.x;
  const int h0 = threadIdx.x * 4;
  const int s0 = slot_of[2 * t], s1 = slot_of[2 * t + 1];
  ushort4 a = *(const ushort4*)(y + (size_t)s0 * H_DIM + h0);
  ushort4 b = *(const ushort4*)(y + (size_t)s1 * H_DIM + h0);
  float4 o;
  o.x = b2f(a.x) + b2f(b.x);
  o.y = b2f(a.y) + b2f(b.y);
  o.z = b2f(a.z) + b2f(b.z);
  o.w = b2f(a.w) + b2f(b.w);
  *(float4*)(out + (size_t)t * H_DIM + h0) = o;
}

// ---------------------------------------------------------------------------
extern "C" void kernel_launch(void* const* d_in, const int* in_sizes, int n_in,
                              void* d_out, int out_size, void* d_ws, size_t ws_size,
                              hipStream_t stream) {
  const float* x  = (const float*)d_in[0];   // [S,B,H] = [8192,1024]
  const float* rw = (const float*)d_in[1];   // [H,E]   = [1024,8]
  const float* w1 = (const float*)d_in[2];   // [E,H,F]
  const float* w2 = (const float*)d_in[3];   // [E,F,H]
  float* out = (float*)d_out;

  char* ws = (char*)d_ws;
  unsigned short* wT     = (unsigned short*)ws;                     // 64 MB (w1t, then w2t)
  unsigned short* xb     = (unsigned short*)(ws + (64ull  << 20));  // 16 MB
  unsigned short* y      = (unsigned short*)(ws + (64ull  << 20));  // 32 MB (reuses dead xb)
  unsigned short* hidden = (unsigned short*)(ws + (96ull  << 20));  // 128 MB
  char* meta = ws + (224ull << 20);
  int*   top_e   = (int*)meta;                     // 16384
  float* top_p   = (float*)(meta + (64 << 10));    // 16384
  int*   map     = (int*)(meta + (128 << 10));     // 16384
  float* gate    = (float*)(meta + (192 << 10));   // 16384
  int*   slot_of = (int*)(meta + (256 << 10));     // 16384
  int*   counts  = (int*)(meta + (320 << 10));     // 8
  int*   offsets = counts + 8;
  int*   cursor  = counts + 16;

  // 1. w1 [E][H][F] fp32 -> wT = w1t [E][F][H] bf16
  transpose_cast_kernel<<<dim3(F_DIM / 64, H_DIM / 64, E_NUM), 256, 0, stream>>>(w1, wT, H_DIM, F_DIM);
  // 2. router (+ x -> bf16)
  router_kernel<<<256, 256, 0, stream>>>(x, rw, xb, top_e, top_p);
  // 3. counts -> offsets
  count_offsets_kernel<<<1, 256, 0, stream>>>(top_e, counts, offsets, cursor);
  // 4. slot assignment
  assign_kernel<<<T_TOKENS / 256, 256, 0, stream>>>(top_e, top_p, offsets, cursor, map, gate, slot_of);
  // 5. fc1: hidden = gelu(x @ w1[e]) over routed slots
  moe_gemm_kernel<H_DIM, F_DIM, true, true>
      <<<dim3(64, F_DIM / 128, E_NUM), 256, 0, stream>>>(xb, wT, map, nullptr, counts, offsets, hidden);
  // 6. w2 [E][F][H] fp32 -> wT = w2t [E][H][F] bf16 (wT free after fc1; stream-serial)
  transpose_cast_kernel<<<dim3(H_DIM / 64, F_DIM / 64, E_NUM), 256, 0, stream>>>(w2, wT, F_DIM, H_DIM);
  // 7. fc2: y = gate * (hidden @ w2[e])
  moe_gemm_kernel<F_DIM, H_DIM, false, false>
      <<<dim3(64, H_DIM / 128, E_NUM), 256, 0, stream>>>(hidden, wT, nullptr, gate, counts, offsets, y);
  // 8. combine two slots per token
  combine_kernel<<<T_TOKENS, 256, 0, stream>>>(y, slot_of, out);
}

// Round 2
// 1112.334 us; speedup vs baseline: 1.1999x; 1.1999x over previous
//
#include <hip/hip_runtime.h>
#include <cstdint>
#include <cstddef>

// Problem dims (fixed)
#define T_TOKENS 8192
#define H_DIM    1024
#define F_DIM    4096
#define E_NUM    8

typedef __bf16 bf16x8 __attribute__((ext_vector_type(8)));
typedef float  f32x4  __attribute__((ext_vector_type(4)));
typedef unsigned short ushort8 __attribute__((ext_vector_type(8)));

#define AS_GLOBAL(p) ((const __attribute__((address_space(1))) void*)(p))
#define AS_LDS(p)    ((__attribute__((address_space(3))) void*)(p))

__device__ inline unsigned short f2b(float f) {
  unsigned int u = __float_as_uint(f);
  unsigned int r = (u + 0x7fffu + ((u >> 16) & 1u)) >> 16;   // RNE
  return (unsigned short)r;
}
__device__ inline float b2f(unsigned short u) {
  return __uint_as_float(((unsigned int)u) << 16);
}
// gelu(v) = 0.5 v (1 + tanh(u)) = v * sigmoid(2u), u = 0.79788456(v + 0.044715 v^3)
__device__ inline float gelu_fast(float v) {
  float u2 = 1.5957691216057308f * v * (1.0f + 0.044715f * v * v);
  return v / (1.0f + __expf(-u2));
}

// ---------------------------------------------------------------------------
// Transpose + fp32->bf16 cast:  in [E][R][C] fp32  ->  out [E][C][R] bf16
// ---------------------------------------------------------------------------
__global__ __launch_bounds__(256) void transpose_cast_kernel(
    const float* __restrict__ in, unsigned short* __restrict__ out, int R, int C)
{
  __shared__ float tile[64][65];
  const int e  = blockIdx.z;
  const int c0 = blockIdx.x * 64;
  const int r0 = blockIdx.y * 64;
  const float* src = in + (size_t)e * R * C;
  unsigned short* dst = out + (size_t)e * R * C;
  const int tid = threadIdx.x;
  const int rl  = tid >> 4;
  const int cl4 = (tid & 15) * 4;
#pragma unroll
  for (int i = 0; i < 4; ++i) {
    float4 v = *(const float4*)(src + (size_t)(r0 + rl + i * 16) * C + c0 + cl4);
    tile[rl + i * 16][cl4 + 0] = v.x;
    tile[rl + i * 16][cl4 + 1] = v.y;
    tile[rl + i * 16][cl4 + 2] = v.z;
    tile[rl + i * 16][cl4 + 3] = v.w;
  }
  __syncthreads();
  const int cl = tid >> 2;
  const int rb = (tid & 3) * 16;
#pragma unroll
  for (int j = 0; j < 4; ++j) {
    ushort4 u;
    u.x = f2b(tile[rb + j * 4 + 0][cl]);
    u.y = f2b(tile[rb + j * 4 + 1][cl]);
    u.z = f2b(tile[rb + j * 4 + 2][cl]);
    u.w = f2b(tile[rb + j * 4 + 3][cl]);
    *(ushort4*)(dst + (size_t)(c0 + cl) * R + r0 + rb + j * 4) = u;
  }
}

// ---------------------------------------------------------------------------
// Router: logits (fp32) -> softmax -> top-2; also casts x to bf16.
// ---------------------------------------------------------------------------
__global__ __launch_bounds__(256) void router_kernel(
    const float* __restrict__ x, const float* __restrict__ rw,
    unsigned short* __restrict__ xb, int* __restrict__ top_e, float* __restrict__ top_p)
{
  __shared__ float lrw[H_DIM * 9];   // padded stride 9 to spread banks
  const int tid = threadIdx.x;
  for (int r = tid; r < H_DIM; r += 256) {
    const float* s = rw + r * 8;
    float4 a = *(const float4*)(s);
    float4 b = *(const float4*)(s + 4);
    float* d = &lrw[r * 9];
    d[0] = a.x; d[1] = a.y; d[2] = a.z; d[3] = a.w;
    d[4] = b.x; d[5] = b.y; d[6] = b.z; d[7] = b.w;
  }
  __syncthreads();
  const int lane = tid & 63, wid = tid >> 6;
  for (int i = 0; i < 8; ++i) {
    const int t = blockIdx.x * 32 + wid * 8 + i;
    float acc[8] = {0.f, 0.f, 0.f, 0.f, 0.f, 0.f, 0.f, 0.f};
    const float* xrow = x + (size_t)t * H_DIM;
    unsigned short* xbrow = xb + (size_t)t * H_DIM;
#pragma unroll
    for (int j = 0; j < 16; ++j) {
      int h = j * 64 + lane;
      float xv = xrow[h];
      xbrow[h] = f2b(xv);
      const float* rr = &lrw[h * 9];
#pragma unroll
      for (int e = 0; e < 8; ++e) acc[e] += xv * rr[e];
    }
#pragma unroll
    for (int e = 0; e < 8; ++e) {
#pragma unroll
      for (int s = 32; s > 0; s >>= 1) acc[e] += __shfl_xor(acc[e], s, 64);
    }
    if (lane == 0) {
      float mx = acc[0];
      for (int e = 1; e < 8; ++e) mx = fmaxf(mx, acc[e]);
      float p[8]; float sum = 0.f;
      for (int e = 0; e < 8; ++e) { p[e] = expf(acc[e] - mx); sum += p[e]; }
      float inv = 1.0f / sum;
      int i1 = 0; float b1 = p[0];
      for (int e = 1; e < 8; ++e) if (p[e] > b1) { b1 = p[e]; i1 = e; }
      int i2 = (i1 == 0) ? 1 : 0; float b2 = p[i2];
      for (int e = 0; e < 8; ++e) if (e != i1 && p[e] > b2) { b2 = p[e]; i2 = e; }
      top_e[2 * t]     = i1; top_p[2 * t]     = b1 * inv;
      top_e[2 * t + 1] = i2; top_p[2 * t + 1] = b2 * inv;
    }
  }
}

// ---------------------------------------------------------------------------
// Count tokens per expert + exclusive prefix -> offsets; zero cursors.
// ---------------------------------------------------------------------------
__global__ __launch_bounds__(256) void count_offsets_kernel(
    const int* __restrict__ top_e, int* __restrict__ counts,
    int* __restrict__ offsets, int* __restrict__ cursor)
{
  __shared__ int c[E_NUM];
  if (threadIdx.x < E_NUM) c[threadIdx.x] = 0;
  __syncthreads();
  for (int i = threadIdx.x; i < 2 * T_TOKENS; i += 256) atomicAdd(&c[top_e[i]], 1);
  __syncthreads();
  if (threadIdx.x == 0) {
    int o = 0;
    for (int e = 0; e < E_NUM; ++e) {
      counts[e] = c[e]; offsets[e] = o; o += c[e]; cursor[e] = 0;
    }
  }
}

// ---------------------------------------------------------------------------
// Dispatch: assign each (token, k) a slot in its expert's contiguous segment.
// ---------------------------------------------------------------------------
__global__ __launch_bounds__(256) void assign_kernel(
    const int* __restrict__ top_e, const float* __restrict__ top_p,
    const int* __restrict__ offsets, int* __restrict__ cursor,
    int* __restrict__ map, float* __restrict__ gate, int* __restrict__ slot_of)
{
  __shared__ int lc[E_NUM], lb[E_NUM];
  const int tid = threadIdx.x;
  const int t = blockIdx.x * 256 + tid;
  if (tid < E_NUM) lc[tid] = 0;
  __syncthreads();
  int e0 = top_e[2 * t], e1 = top_e[2 * t + 1];
  int p0 = atomicAdd(&lc[e0], 1);
  int p1 = atomicAdd(&lc[e1], 1);
  __syncthreads();
  if (tid < E_NUM) lb[tid] = atomicAdd(&cursor[tid], lc[tid]);
  __syncthreads();
  int s0 = offsets[e0] + lb[e0] + p0;
  int s1 = offsets[e1] + lb[e1] + p1;
  map[s0] = t; gate[s0] = top_p[2 * t];
  map[s1] = t; gate[s1] = top_p[2 * t + 1];
  slot_of[2 * t] = s0; slot_of[2 * t + 1] = s1;
}

// ---------------------------------------------------------------------------
// Grouped GEMM: 128x128 tile, BK=64, 4 waves of 64x64, mfma 16x16x32 bf16,
// global_load_lds width-16 staging with XOR chunk swizzle (kills the
// stride-128B 16-way bank conflict; residual 2-way aliasing is free).
// LDS layout: row r holds global chunk g at position g ^ (r&7)  (16B chunks).
// Staging keeps the lane-contiguous LDS-destination constraint: swizzle is
// applied to the *global source* column, which stays within one 128B row.
// Epilogue: fast gelu / gate, LDS repack (stride 136 shorts, 16B aligned),
// then 16B coalesced global stores.
// ---------------------------------------------------------------------------
template <int KD, int ND, bool USE_MAP, bool GELU>
__global__ __launch_bounds__(256) void moe_gemm_kernel(
    const unsigned short* __restrict__ A, const unsigned short* __restrict__ Bt,
    const int* __restrict__ map, const float* __restrict__ gate,
    const int* __restrict__ counts, const int* __restrict__ offsets,
    unsigned short* __restrict__ C)
{
  __shared__ unsigned short ls[128 * 136];       // 34.8 KB; staging uses first 32 KB
  unsigned short* lsA = ls;                      // 128 x 64
  unsigned short* lsB = ls + 128 * 64;           // 128 x 64
  const int e   = blockIdx.z;
  const int cnt = counts[e];
  const int tile_m = blockIdx.x;
  if (tile_m * 128 >= cnt) return;
  const int off    = offsets[e];
  const int tile_n = blockIdx.y;
  const int tid    = threadIdx.x;

  // Staging: chunk = it*256+tid ; row = chunk>>3 ; global chunk = (tid&7)^(row&7)
  const unsigned short* aSrc[4];
  const unsigned short* bSrc[4];
  const int cswz = ((tid & 7) ^ ((tid >> 3) & 7)) * 8;
#pragma unroll
  for (int it = 0; it < 4; ++it) {
    int r  = it * 32 + (tid >> 3);
    int rm = tile_m * 128 + r;
    if (rm > cnt - 1) rm = cnt - 1;               // clamp padded rows
    int arow = USE_MAP ? map[off + rm] : (off + rm);
    aSrc[it] = A + (size_t)arow * KD + cswz;
    int rn = tile_n * 128 + r;
    bSrc[it] = Bt + (size_t)e * ND * KD + (size_t)rn * KD + cswz;
  }

  const int lane = tid & 63;
  const int wid  = tid >> 6;
  const int wm = wid >> 1, wn = wid & 1;          // 2x2 wave grid, 64x64 each
  const int lr = lane & 15, kg = lane >> 4;
  const int swz = lr & 7;                          // fragment read de-swizzle
  const unsigned short* pA = lsA + (wm * 64 + lr) * 64;
  const unsigned short* pB = lsB + (wn * 64 + lr) * 64;

  f32x4 acc[4][4];
#pragma unroll
  for (int mi = 0; mi < 4; ++mi)
#pragma unroll
    for (int ni = 0; ni < 4; ++ni) acc[mi][ni] = (f32x4){0.f, 0.f, 0.f, 0.f};

#pragma unroll 1
  for (int k0 = 0; k0 < KD; k0 += 64) {
    __syncthreads();
#pragma unroll
    for (int it = 0; it < 4; ++it)
      __builtin_amdgcn_global_load_lds(AS_GLOBAL(aSrc[it] + k0),
                                       AS_LDS(lsA + (it * 256 + tid) * 8), 16, 0, 0);
#pragma unroll
    for (int it = 0; it < 4; ++it)
      __builtin_amdgcn_global_load_lds(AS_GLOBAL(bSrc[it] + k0),
                                       AS_LDS(lsB + (it * 256 + tid) * 8), 16, 0, 0);
    __syncthreads();
#pragma unroll
    for (int ks = 0; ks < 2; ++ks) {
      bf16x8 aF[4], bF[4];
#pragma unroll
      for (int i = 0; i < 4; ++i)
        aF[i] = *(const bf16x8*)(pA + i * 16 * 64 + (((ks * 4 + kg) ^ swz) * 8));
#pragma unroll
      for (int i = 0; i < 4; ++i)
        bF[i] = *(const bf16x8*)(pB + i * 16 * 64 + (((ks * 4 + kg) ^ swz) * 8));
#pragma unroll
      for (int mi = 0; mi < 4; ++mi)
#pragma unroll
        for (int ni = 0; ni < 4; ++ni)
          acc[mi][ni] = __builtin_amdgcn_mfma_f32_16x16x32_bf16(aF[mi], bF[ni],
                                                                acc[mi][ni], 0, 0, 0);
    }
  }

  // ---- Epilogue: activation/gate -> LDS repack -> coalesced 16B stores ----
  __syncthreads();
#pragma unroll
  for (int mi = 0; mi < 4; ++mi) {
#pragma unroll
    for (int r = 0; r < 4; ++r) {
      int Rl = wm * 64 + mi * 16 + kg * 4 + r;
      float gv = 1.0f;
      if (!GELU) {
        int gm = tile_m * 128 + Rl;
        int gmc = gm < cnt ? gm : cnt - 1;
        gv = gate[off + gmc];
      }
#pragma unroll
      for (int ni = 0; ni < 4; ++ni) {
        int col = wn * 64 + ni * 16 + lr;
        float v = acc[mi][ni][r];
        v = GELU ? gelu_fast(v) : v * gv;
        ls[Rl * 136 + col] = f2b(v);
      }
    }
  }
  __syncthreads();
#pragma unroll
  for (int it = 0; it < 8; ++it) {
    int g = it * 256 + tid;
    int R = g >> 4, c16 = g & 15;
    int gm = tile_m * 128 + R;
    if (gm < cnt) {
      ushort8 v = *(const ushort8*)(ls + R * 136 + c16 * 8);
      *(ushort8*)(C + (size_t)(off + gm) * ND + tile_n * 128 + c16 * 8) = v;
    }
  }
}

// ---------------------------------------------------------------------------
// Combine: out[t] = y[slot0(t)] + y[slot1(t)]   (gates already applied)
// ---------------------------------------------------------------------------
__global__ __launch_bounds__(256) void combine_kernel(
    const unsigned short* __restrict__ y, const int* __restrict__ slot_of,
    float* __restrict__ out)
{
  const int t  = blockIdx.x;
  const int h0 = threadIdx.x * 4;
  const int s0 = slot_of[2 * t], s1 = slot_of[2 * t + 1];
  ushort4 a = *(const ushort4*)(y + (size_t)s0 * H_DIM + h0);
  ushort4 b = *(const ushort4*)(y + (size_t)s1 * H_DIM + h0);
  float4 o;
  o.x = b2f(a.x) + b2f(b.x);
  o.y = b2f(a.y) + b2f(b.y);
  o.z = b2f(a.z) + b2f(b.z);
  o.w = b2f(a.w) + b2f(b.w);
  *(float4*)(out + (size_t)t * H_DIM + h0) = o;
}

// ---------------------------------------------------------------------------
extern "C" void kernel_launch(void* const* d_in, const int* in_sizes, int n_in,
                              void* d_out, int out_size, void* d_ws, size_t ws_size,
                              hipStream_t stream) {
  const float* x  = (const float*)d_in[0];   // [S,B,H] = [8192,1024]
  const float* rw = (const float*)d_in[1];   // [H,E]   = [1024,8]
  const float* w1 = (const float*)d_in[2];   // [E,H,F]
  const float* w2 = (const float*)d_in[3];   // [E,F,H]
  float* out = (float*)d_out;

  char* ws = (char*)d_ws;
  unsigned short* wT     = (unsigned short*)ws;                     // 64 MB (w1t, then w2t)
  unsigned short* xb     = (unsigned short*)(ws + (64ull  << 20));  // 16 MB
  unsigned short* y      = (unsigned short*)(ws + (64ull  << 20));  // 32 MB (reuses dead xb)
  unsigned short* hidden = (unsigned short*)(ws + (96ull  << 20));  // 128 MB
  char* meta = ws + (224ull << 20);
  int*   top_e   = (int*)meta;                     // 16384
  float* top_p   = (float*)(meta + (64 << 10));    // 16384
  int*   map     = (int*)(meta + (128 << 10));     // 16384
  float* gate    = (float*)(meta + (192 << 10));   // 16384
  int*   slot_of = (int*)(meta + (256 << 10));     // 16384
  int*   counts  = (int*)(meta + (320 << 10));     // 8
  int*   offsets = counts + 8;
  int*   cursor  = counts + 16;

  // 1. w1 [E][H][F] fp32 -> wT = w1t [E][F][H] bf16
  transpose_cast_kernel<<<dim3(F_DIM / 64, H_DIM / 64, E_NUM), 256, 0, stream>>>(w1, wT, H_DIM, F_DIM);
  // 2. router (+ x -> bf16)
  router_kernel<<<256, 256, 0, stream>>>(x, rw, xb, top_e, top_p);
  // 3. counts -> offsets
  count_offsets_kernel<<<1, 256, 0, stream>>>(top_e, counts, offsets, cursor);
  // 4. slot assignment
  assign_kernel<<<T_TOKENS / 256, 256, 0, stream>>>(top_e, top_p, offsets, cursor, map, gate, slot_of);
  // 5. fc1: hidden = gelu(x @ w1[e]) over routed slots
  moe_gemm_kernel<H_DIM, F_DIM, true, true>
      <<<dim3(64, F_DIM / 128, E_NUM), 256, 0, stream>>>(xb, wT, map, nullptr, counts, offsets, hidden);
  // 6. w2 [E][F][H] fp32 -> wT = w2t [E][H][F] bf16 (wT free after fc1; stream-serial)
  transpose_cast_kernel<<<dim3(H_DIM / 64, F_DIM / 64, E_NUM), 256, 0, stream>>>(w2, wT, F_DIM, H_DIM);
  // 7. fc2: y = gate * (hidden @ w2[e])
  moe_gemm_kernel<F_DIM, H_DIM, false, false>
      <<<dim3(64, H_DIM / 128, E_NUM), 256, 0, stream>>>(hidden, wT, nullptr, gate, counts, offsets, y);
  // 8. combine two slots per token
  combine_kernel<<<T_TOKENS, 256, 0, stream>>>(y, slot_of, out);
}

// Round 3
// 751.235 us; speedup vs baseline: 1.7766x; 1.4807x over previous
//
#include <hip/hip_runtime.h>
#include <cstdint>
#include <cstddef>

// Problem dims (fixed)
#define T_TOKENS 8192
#define H_DIM    1024
#define F_DIM    4096
#define E_NUM    8

typedef __bf16 bf16x8 __attribute__((ext_vector_type(8)));
typedef float  f32x4  __attribute__((ext_vector_type(4)));
typedef unsigned short ushort8 __attribute__((ext_vector_type(8)));

#define AS_GLOBAL(p) ((const __attribute__((address_space(1))) void*)(p))
#define AS_LDS(p)    ((__attribute__((address_space(3))) void*)(p))

__device__ inline unsigned short f2b(float f) {
  unsigned int u = __float_as_uint(f);
  unsigned int r = (u + 0x7fffu + ((u >> 16) & 1u)) >> 16;   // RNE
  return (unsigned short)r;
}
__device__ inline float b2f(unsigned short u) {
  return __uint_as_float(((unsigned int)u) << 16);
}
// gelu(v) = 0.5 v (1 + tanh(u)) = v * sigmoid(2u), u = 0.79788456(v + 0.044715 v^3)
__device__ inline float gelu_fast(float v) {
  float u2 = 1.5957691216057308f * v * (1.0f + 0.044715f * v * v);
  return v / (1.0f + __expf(-u2));
}

// ---------------------------------------------------------------------------
// Transpose + fp32->bf16 cast:  in [E][R][C] fp32  ->  out [E][C][R] bf16
// ---------------------------------------------------------------------------
__global__ __launch_bounds__(256) void transpose_cast_kernel(
    const float* __restrict__ in, unsigned short* __restrict__ out, int R, int C)
{
  __shared__ float tile[64][65];
  const int e  = blockIdx.z;
  const int c0 = blockIdx.x * 64;
  const int r0 = blockIdx.y * 64;
  const float* src = in + (size_t)e * R * C;
  unsigned short* dst = out + (size_t)e * R * C;
  const int tid = threadIdx.x;
  const int rl  = tid >> 4;
  const int cl4 = (tid & 15) * 4;
#pragma unroll
  for (int i = 0; i < 4; ++i) {
    float4 v = *(const float4*)(src + (size_t)(r0 + rl + i * 16) * C + c0 + cl4);
    tile[rl + i * 16][cl4 + 0] = v.x;
    tile[rl + i * 16][cl4 + 1] = v.y;
    tile[rl + i * 16][cl4 + 2] = v.z;
    tile[rl + i * 16][cl4 + 3] = v.w;
  }
  __syncthreads();
  const int cl = tid >> 2;
  const int rb = (tid & 3) * 16;
#pragma unroll
  for (int j = 0; j < 4; ++j) {
    ushort4 u;
    u.x = f2b(tile[rb + j * 4 + 0][cl]);
    u.y = f2b(tile[rb + j * 4 + 1][cl]);
    u.z = f2b(tile[rb + j * 4 + 2][cl]);
    u.w = f2b(tile[rb + j * 4 + 3][cl]);
    *(ushort4*)(dst + (size_t)(c0 + cl) * R + r0 + rb + j * 4) = u;
  }
}

// ---------------------------------------------------------------------------
// Zero the routing counters (d_ws is poisoned before every call).
// ---------------------------------------------------------------------------
__global__ void zero_meta_kernel(int* __restrict__ counts) {
  if (threadIdx.x < 24) counts[threadIdx.x] = 0;   // counts[8], offsets[8], cursor[8]
}

// ---------------------------------------------------------------------------
// Router: logits (fp32) -> softmax -> top-2; casts x to bf16; block-aggregated
// expert counts -> global atomics (replaces the serial 16K-scan count kernel).
// ---------------------------------------------------------------------------
__global__ __launch_bounds__(256) void router_kernel(
    const float* __restrict__ x, const float* __restrict__ rw,
    unsigned short* __restrict__ xb, int* __restrict__ top_e, float* __restrict__ top_p,
    int* __restrict__ counts)
{
  __shared__ float lrw[H_DIM * 9];   // padded stride 9 to spread banks
  __shared__ int lc[E_NUM];
  const int tid = threadIdx.x;
  if (tid < E_NUM) lc[tid] = 0;
  for (int r = tid; r < H_DIM; r += 256) {
    const float* s = rw + r * 8;
    float4 a = *(const float4*)(s);
    float4 b = *(const float4*)(s + 4);
    float* d = &lrw[r * 9];
    d[0] = a.x; d[1] = a.y; d[2] = a.z; d[3] = a.w;
    d[4] = b.x; d[5] = b.y; d[6] = b.z; d[7] = b.w;
  }
  __syncthreads();
  const int lane = tid & 63, wid = tid >> 6;
  for (int i = 0; i < 8; ++i) {
    const int t = blockIdx.x * 32 + wid * 8 + i;
    float acc[8] = {0.f, 0.f, 0.f, 0.f, 0.f, 0.f, 0.f, 0.f};
    const float* xrow = x + (size_t)t * H_DIM;
    unsigned short* xbrow = xb + (size_t)t * H_DIM;
#pragma unroll
    for (int j = 0; j < 16; ++j) {
      int h = j * 64 + lane;
      float xv = xrow[h];
      xbrow[h] = f2b(xv);
      const float* rr = &lrw[h * 9];
#pragma unroll
      for (int e = 0; e < 8; ++e) acc[e] += xv * rr[e];
    }
#pragma unroll
    for (int e = 0; e < 8; ++e) {
#pragma unroll
      for (int s = 32; s > 0; s >>= 1) acc[e] += __shfl_xor(acc[e], s, 64);
    }
    if (lane == 0) {
      float mx = acc[0];
      for (int e = 1; e < 8; ++e) mx = fmaxf(mx, acc[e]);
      float p[8]; float sum = 0.f;
      for (int e = 0; e < 8; ++e) { p[e] = expf(acc[e] - mx); sum += p[e]; }
      float inv = 1.0f / sum;
      int i1 = 0; float b1 = p[0];
      for (int e = 1; e < 8; ++e) if (p[e] > b1) { b1 = p[e]; i1 = e; }
      int i2 = (i1 == 0) ? 1 : 0; float b2 = p[i2];
      for (int e = 0; e < 8; ++e) if (e != i1 && p[e] > b2) { b2 = p[e]; i2 = e; }
      top_e[2 * t]     = i1; top_p[2 * t]     = b1 * inv;
      top_e[2 * t + 1] = i2; top_p[2 * t + 1] = b2 * inv;
      atomicAdd(&lc[i1], 1);
      atomicAdd(&lc[i2], 1);
    }
  }
  __syncthreads();
  if (tid < E_NUM) atomicAdd(&counts[tid], lc[tid]);
}

// ---------------------------------------------------------------------------
// Tiny: exclusive prefix over 8 counts -> offsets; zero cursors.
// ---------------------------------------------------------------------------
__global__ void offsets_kernel(const int* __restrict__ counts,
                               int* __restrict__ offsets, int* __restrict__ cursor) {
  if (threadIdx.x == 0) {
    int o = 0;
    for (int e = 0; e < E_NUM; ++e) { offsets[e] = o; o += counts[e]; cursor[e] = 0; }
  }
}

// ---------------------------------------------------------------------------
// Dispatch: assign each (token, k) a slot in its expert's contiguous segment.
// ---------------------------------------------------------------------------
__global__ __launch_bounds__(256) void assign_kernel(
    const int* __restrict__ top_e, const float* __restrict__ top_p,
    const int* __restrict__ offsets, int* __restrict__ cursor,
    int* __restrict__ map, float* __restrict__ gate, int* __restrict__ slot_of)
{
  __shared__ int lc[E_NUM], lb[E_NUM];
  const int tid = threadIdx.x;
  const int t = blockIdx.x * 256 + tid;
  if (tid < E_NUM) lc[tid] = 0;
  __syncthreads();
  int e0 = top_e[2 * t], e1 = top_e[2 * t + 1];
  int p0 = atomicAdd(&lc[e0], 1);
  int p1 = atomicAdd(&lc[e1], 1);
  __syncthreads();
  if (tid < E_NUM) lb[tid] = atomicAdd(&cursor[tid], lc[tid]);
  __syncthreads();
  int s0 = offsets[e0] + lb[e0] + p0;
  int s1 = offsets[e1] + lb[e1] + p1;
  map[s0] = t; gate[s0] = top_p[2 * t];
  map[s1] = t; gate[s1] = top_p[2 * t + 1];
  slot_of[2 * t] = s0; slot_of[2 * t + 1] = s1;
}

// ---------------------------------------------------------------------------
// Grouped GEMM: 128x128 tile, BK=64, 4 waves of 64x64, mfma 16x16x32 bf16.
// Double-buffered LDS (2x32KB): loads for iter k+1 issued before computing
// iter k; manual `s_waitcnt vmcnt(8)` waits only the PREVIOUS iter's 8
// global_load_lds (the new 8 stay in flight across the whole compute phase)
// -- hides the ~900cyc HBM-miss latency the m97 vmcnt(0)-barrier exposes.
// Raw s_barrier (m139-style) so the compiler doesn't re-insert vmcnt(0).
// XOR chunk swizzle kills the stride-128B bank conflict (round-2 win).
// Grid: (e=8, m=64, n): linear_id % 8 == e -> expert pinned to one XCD;
// n outermost so the B n-slab stays hot in that XCD's L2 across m-tiles.
// ---------------------------------------------------------------------------
template <int KD, int ND, bool USE_MAP, bool GELU>
__global__ __launch_bounds__(256) void moe_gemm_kernel(
    const unsigned short* __restrict__ A, const unsigned short* __restrict__ Bt,
    const int* __restrict__ map, const float* __restrict__ gate,
    const int* __restrict__ counts, const int* __restrict__ offsets,
    unsigned short* __restrict__ C)
{
  __shared__ unsigned short ls[32768];           // 64 KB: [A0|A1|B0|B1] 8192 shorts each
  const int e   = blockIdx.x;
  const int cnt = counts[e];
  const int tile_m = blockIdx.y;
  if (tile_m * 128 >= cnt) return;
  const int off    = offsets[e];
  const int tile_n = blockIdx.z;
  const int tid    = threadIdx.x;

  // Staging: chunk = it*256+tid ; row = chunk>>3 ; global chunk = (tid&7)^(row&7)
  const unsigned short* aSrc[4];
  const unsigned short* bSrc[4];
  const int cswz = ((tid & 7) ^ ((tid >> 3) & 7)) * 8;
#pragma unroll
  for (int it = 0; it < 4; ++it) {
    int r  = it * 32 + (tid >> 3);
    int rm = tile_m * 128 + r;
    if (rm > cnt - 1) rm = cnt - 1;               // clamp padded rows
    int arow = USE_MAP ? map[off + rm] : (off + rm);
    aSrc[it] = A + (size_t)arow * KD + cswz;
    int rn = tile_n * 128 + r;
    bSrc[it] = Bt + (size_t)e * ND * KD + (size_t)rn * KD + cswz;
  }

  const int lane = tid & 63;
  const int wid  = tid >> 6;
  const int wm = wid >> 1, wn = wid & 1;          // 2x2 wave grid, 64x64 each
  const int lr = lane & 15, kg = lane >> 4;
  const int swz = lr & 7;                          // fragment read de-swizzle

  f32x4 acc[4][4];
#pragma unroll
  for (int mi = 0; mi < 4; ++mi)
#pragma unroll
    for (int ni = 0; ni < 4; ++ni) acc[mi][ni] = (f32x4){0.f, 0.f, 0.f, 0.f};

  constexpr int NK = KD / 64;

  // prologue: issue iter-0 loads into buffer 0
#pragma unroll
  for (int it = 0; it < 4; ++it)
    __builtin_amdgcn_global_load_lds(AS_GLOBAL(aSrc[it]),
                                     AS_LDS(ls + (it * 256 + tid) * 8), 16, 0, 0);
#pragma unroll
  for (int it = 0; it < 4; ++it)
    __builtin_amdgcn_global_load_lds(AS_GLOBAL(bSrc[it]),
                                     AS_LDS(ls + 16384 + (it * 256 + tid) * 8), 16, 0, 0);

#pragma unroll 1
  for (int k = 0; k < NK; ++k) {
    const int p = k & 1;
    // barrier 1: everyone finished reading buffer p^1 (iter k-1 compute)
    asm volatile("s_barrier" ::: "memory");
    if (k + 1 < NK) {
      const int q = p ^ 1;
      const int k0 = (k + 1) * 64;
#pragma unroll
      for (int it = 0; it < 4; ++it)
        __builtin_amdgcn_global_load_lds(AS_GLOBAL(aSrc[it] + k0),
                                         AS_LDS(ls + q * 8192 + (it * 256 + tid) * 8), 16, 0, 0);
#pragma unroll
      for (int it = 0; it < 4; ++it)
        __builtin_amdgcn_global_load_lds(AS_GLOBAL(bSrc[it] + k0),
                                         AS_LDS(ls + 16384 + q * 8192 + (it * 256 + tid) * 8), 16, 0, 0);
      asm volatile("s_waitcnt vmcnt(8)" ::: "memory");   // wait iter-k loads only
    } else {
      asm volatile("s_waitcnt vmcnt(0)" ::: "memory");
    }
    // barrier 2: all waves' buffer-p loads complete
    asm volatile("s_barrier" ::: "memory");

    const unsigned short* pA = ls + p * 8192 + (wm * 64 + lr) * 64;
    const unsigned short* pB = ls + 16384 + p * 8192 + (wn * 64 + lr) * 64;
#pragma unroll
    for (int ks = 0; ks < 2; ++ks) {
      bf16x8 aF[4], bF[4];
#pragma unroll
      for (int i = 0; i < 4; ++i)
        aF[i] = *(const bf16x8*)(pA + i * 16 * 64 + (((ks * 4 + kg) ^ swz) * 8));
#pragma unroll
      for (int i = 0; i < 4; ++i)
        bF[i] = *(const bf16x8*)(pB + i * 16 * 64 + (((ks * 4 + kg) ^ swz) * 8));
#pragma unroll
      for (int mi = 0; mi < 4; ++mi)
#pragma unroll
        for (int ni = 0; ni < 4; ++ni)
          acc[mi][ni] = __builtin_amdgcn_mfma_f32_16x16x32_bf16(aF[mi], bF[ni],
                                                                acc[mi][ni], 0, 0, 0);
    }
  }

  // ---- Epilogue: activation/gate -> LDS repack -> coalesced 16B stores ----
  __syncthreads();
#pragma unroll
  for (int mi = 0; mi < 4; ++mi) {
#pragma unroll
    for (int r = 0; r < 4; ++r) {
      int Rl = wm * 64 + mi * 16 + kg * 4 + r;
      float gv = 1.0f;
      if (!GELU) {
        int gm = tile_m * 128 + Rl;
        int gmc = gm < cnt ? gm : cnt - 1;
        gv = gate[off + gmc];
      }
#pragma unroll
      for (int ni = 0; ni < 4; ++ni) {
        int col = wn * 64 + ni * 16 + lr;
        float v = acc[mi][ni][r];
        v = GELU ? gelu_fast(v) : v * gv;
        ls[Rl * 136 + col] = f2b(v);
      }
    }
  }
  __syncthreads();
#pragma unroll
  for (int it = 0; it < 8; ++it) {
    int g = it * 256 + tid;
    int R = g >> 4, c16 = g & 15;
    int gm = tile_m * 128 + R;
    if (gm < cnt) {
      ushort8 v = *(const ushort8*)(ls + R * 136 + c16 * 8);
      *(ushort8*)(C + (size_t)(off + gm) * ND + tile_n * 128 + c16 * 8) = v;
    }
  }
}

// ---------------------------------------------------------------------------
// Combine: out[t] = y[slot0(t)] + y[slot1(t)]   (gates already applied)
// ---------------------------------------------------------------------------
__global__ __launch_bounds__(256) void combine_kernel(
    const unsigned short* __restrict__ y, const int* __restrict__ slot_of,
    float* __restrict__ out)
{
  const int t  = blockIdx.x;
  const int h0 = threadIdx.x * 4;
  const int s0 = slot_of[2 * t], s1 = slot_of[2 * t + 1];
  ushort4 a = *(const ushort4*)(y + (size_t)s0 * H_DIM + h0);
  ushort4 b = *(const ushort4*)(y + (size_t)s1 * H_DIM + h0);
  float4 o;
  o.x = b2f(a.x) + b2f(b.x);
  o.y = b2f(a.y) + b2f(b.y);
  o.z = b2f(a.z) + b2f(b.z);
  o.w = b2f(a.w) + b2f(b.w);
  *(float4*)(out + (size_t)t * H_DIM + h0) = o;
}

// ---------------------------------------------------------------------------
extern "C" void kernel_launch(void* const* d_in, const int* in_sizes, int n_in,
                              void* d_out, int out_size, void* d_ws, size_t ws_size,
                              hipStream_t stream) {
  const float* x  = (const float*)d_in[0];   // [S,B,H] = [8192,1024]
  const float* rw = (const float*)d_in[1];   // [H,E]   = [1024,8]
  const float* w1 = (const float*)d_in[2];   // [E,H,F]
  const float* w2 = (const float*)d_in[3];   // [E,F,H]
  float* out = (float*)d_out;

  char* ws = (char*)d_ws;
  unsigned short* wT     = (unsigned short*)ws;                     // 64 MB (w1t, then w2t)
  unsigned short* xb     = (unsigned short*)(ws + (64ull  << 20));  // 16 MB
  unsigned short* y      = (unsigned short*)(ws + (64ull  << 20));  // 32 MB (reuses dead xb)
  unsigned short* hidden = (unsigned short*)(ws + (96ull  << 20));  // 128 MB
  char* meta = ws + (224ull << 20);
  int*   top_e   = (int*)meta;                     // 16384
  float* top_p   = (float*)(meta + (64 << 10));    // 16384
  int*   map     = (int*)(meta + (128 << 10));     // 16384
  float* gate    = (float*)(meta + (192 << 10));   // 16384
  int*   slot_of = (int*)(meta + (256 << 10));     // 16384
  int*   counts  = (int*)(meta + (320 << 10));     // 8
  int*   offsets = counts + 8;
  int*   cursor  = counts + 16;

  // 0. zero routing counters (ws is poisoned each call)
  zero_meta_kernel<<<1, 64, 0, stream>>>(counts);
  // 1. w1 [E][H][F] fp32 -> wT = w1t [E][F][H] bf16
  transpose_cast_kernel<<<dim3(F_DIM / 64, H_DIM / 64, E_NUM), 256, 0, stream>>>(w1, wT, H_DIM, F_DIM);
  // 2. router (+ x -> bf16, + per-block expert counts)
  router_kernel<<<256, 256, 0, stream>>>(x, rw, xb, top_e, top_p, counts);
  // 3. offsets from counts
  offsets_kernel<<<1, 64, 0, stream>>>(counts, offsets, cursor);
  // 4. slot assignment
  assign_kernel<<<T_TOKENS / 256, 256, 0, stream>>>(top_e, top_p, offsets, cursor, map, gate, slot_of);
  // 5. fc1: hidden = gelu(x @ w1[e]) over routed slots
  moe_gemm_kernel<H_DIM, F_DIM, true, true>
      <<<dim3(E_NUM, 64, F_DIM / 128), 256, 0, stream>>>(xb, wT, map, nullptr, counts, offsets, hidden);
  // 6. w2 [E][F][H] fp32 -> wT = w2t [E][H][F] bf16 (wT free after fc1; stream-serial)
  transpose_cast_kernel<<<dim3(H_DIM / 64, F_DIM / 64, E_NUM), 256, 0, stream>>>(w2, wT, F_DIM, H_DIM);
  // 7. fc2: y = gate * (hidden @ w2[e])
  moe_gemm_kernel<F_DIM, H_DIM, false, false>
      <<<dim3(E_NUM, 64, H_DIM / 128), 256, 0, stream>>>(hidden, wT, nullptr, gate, counts, offsets, y);
  // 8. combine two slots per token
  combine_kernel<<<T_TOKENS, 256, 0, stream>>>(y, slot_of, out);
}